// Round 2
// baseline (613.783 us; speedup 1.0000x reference)
//
#include <hip/hip_runtime.h>
#include <math.h>

#define D      2048
#define NR     32
#define MROWS  16
#define SDW    514   // dwords per hs row (2056 B); 514%32==2 -> phase-B banks spread {0,8,16,24}

typedef float v2f __attribute__((ext_vector_type(2)));

__device__ __forceinline__ void fma4(float a, const float4& w, float4& o) {
    o.x = fmaf(a, w.x, o.x);
    o.y = fmaf(a, w.y, o.y);
    o.z = fmaf(a, w.z, o.z);
    o.w = fmaf(a, w.w, o.w);
}

__global__ __launch_bounds__(256, 4)
void adapter_fused(const float* __restrict__ x,
                   const float* __restrict__ gamma,
                   const float* __restrict__ beta,
                   const float* __restrict__ wd,
                   const float* __restrict__ bd,
                   const float* __restrict__ wu,
                   const float* __restrict__ bu,
                   float* __restrict__ out)
{
    __shared__ unsigned int hs[MROWS * SDW];    // normalized h, fp8 e4m3, 4/dword
    __shared__ float yacc[MROWS * NR];          // down-proj accumulator
    __shared__ float amat[MROWS * NR];          // gelu output

    const int tid = threadIdx.x;
    const long row0 = (long)blockIdx.x * MROWS;

    yacc[tid] = 0.0f;
    yacc[tid + 256] = 0.0f;

    // ---------------- Phase A: LayerNorm -> hs (fp8 in LDS) ----------------
    {
        const int jg = tid & 15;     // 16 j-groups per row
        const int m  = tid >> 4;     // 16 rows
        const float* xr = x + (row0 + m) * D;
        float s = 0.f, s2 = 0.f;
        #pragma unroll 8
        for (int it = 0; it < 32; ++it) {
            const int j = it * 64 + jg * 4;
            float4 v = *(const float4*)(xr + j);
            s  += v.x + v.y + v.z + v.w;
            s2 += v.x * v.x + v.y * v.y + v.z * v.z + v.w * v.w;
        }
        #pragma unroll
        for (int off = 1; off < 16; off <<= 1) {
            s  += __shfl_xor(s, off);
            s2 += __shfl_xor(s2, off);
        }
        const float mu   = s * (1.0f / D);
        const float var  = s2 * (1.0f / D) - mu * mu;
        const float rstd = rsqrtf(var + 1e-5f);
        #pragma unroll 4
        for (int it = 0; it < 32; ++it) {
            const int j = it * 64 + jg * 4;
            float4 v = *(const float4*)(xr + j);
            float4 g = *(const float4*)(gamma + j);
            float4 b = *(const float4*)(beta + j);
            float h0 = (v.x - mu) * rstd * g.x + b.x;
            float h1 = (v.y - mu) * rstd * g.y + b.y;
            float h2 = (v.z - mu) * rstd * g.z + b.z;
            float h3 = (v.w - mu) * rstd * g.w + b.w;
            unsigned int p = (unsigned int)__builtin_amdgcn_cvt_pk_fp8_f32(h0, h1, 0, false);
            p = (unsigned int)__builtin_amdgcn_cvt_pk_fp8_f32(h2, h3, (int)p, true);
            hs[m * SDW + it * 16 + jg] = p;
        }
    }
    __syncthreads();

    // ---------------- Phase B: down-proj  y = h @ wd ----------------
    {
        const int rg = tid & 7;          // 8 groups x 4 r
        const int mg = (tid >> 3) & 3;   // 4 groups x 4 rows
        const int ks = tid >> 5;         // 8 k-splits x 256
        const int r0 = rg * 4;
        const int m0 = mg * 4;

        float4 acc4[4];
        #pragma unroll
        for (int i = 0; i < 4; ++i) acc4[i] = make_float4(0.f, 0.f, 0.f, 0.f);

        const int kbeg = ks * 256;
        for (int k = kbeg; k < kbeg + 256; k += 4) {
            const float4* wp = (const float4*)(wd + k * NR + r0);
            float4 w0 = wp[0];
            float4 w1 = wp[8];       // +1 k-row (32 floats)
            float4 w2 = wp[16];
            float4 w3 = wp[24];
            #pragma unroll
            for (int i = 0; i < 4; ++i) {
                unsigned int hp = hs[(m0 + i) * SDW + (k >> 2)];
                v2f lo = __builtin_amdgcn_cvt_pk_f32_fp8((int)hp, false);
                v2f hi = __builtin_amdgcn_cvt_pk_f32_fp8((int)hp, true);
                fma4(lo.x, w0, acc4[i]);
                fma4(lo.y, w1, acc4[i]);
                fma4(hi.x, w2, acc4[i]);
                fma4(hi.y, w3, acc4[i]);
            }
        }
        // combine ks-split pairs within the wave (lane ^ 32 flips ks by 1)
        #pragma unroll
        for (int i = 0; i < 4; ++i) {
            acc4[i].x += __shfl_xor(acc4[i].x, 32);
            acc4[i].y += __shfl_xor(acc4[i].y, 32);
            acc4[i].z += __shfl_xor(acc4[i].z, 32);
            acc4[i].w += __shfl_xor(acc4[i].w, 32);
        }
        if ((tid & 32) == 0) {
            #pragma unroll
            for (int i = 0; i < 4; ++i) {
                float* yp = &yacc[(m0 + i) * NR + r0];
                atomicAdd(yp + 0, acc4[i].x);
                atomicAdd(yp + 1, acc4[i].y);
                atomicAdd(yp + 2, acc4[i].z);
                atomicAdd(yp + 3, acc4[i].w);
            }
        }
    }
    __syncthreads();

    // ---------------- GELU (exact) ----------------
    {
        #pragma unroll
        for (int e = 0; e < 2; ++e) {
            const int idx = tid + e * 256;
            const float v = yacc[idx] + bd[idx & (NR - 1)];
            amat[idx] = 0.5f * v * (1.0f + erff(v * 0.70710678118654752f));
        }
    }
    __syncthreads();

    // ---------------- Phase C: up-proj + residual (contiguous 1KB/wave-inst) ----------------
    {
        const int jg = tid & 63;     // wave = 64 consecutive float4 chunks
        const int mg = tid >> 6;     // 4 row-groups x 4 rows
        const int m0 = mg * 4;
        for (int jt = 0; jt < 8; ++jt) {
            const int j0 = jt * 256 + jg * 4;
            float4 bv = *(const float4*)(bu + j0);
            float4 o[4];
            #pragma unroll
            for (int i = 0; i < 4; ++i) {
                float4 xv = *(const float4*)(x + (row0 + m0 + i) * D + j0);
                o[i] = make_float4(xv.x + bv.x, xv.y + bv.y, xv.z + bv.z, xv.w + bv.w);
            }
            for (int r = 0; r < NR; r += 4) {
                float a4[4][4];
                #pragma unroll
                for (int i = 0; i < 4; ++i) {
                    float4 t = *(const float4*)(&amat[(m0 + i) * NR + r]);
                    a4[i][0] = t.x; a4[i][1] = t.y; a4[i][2] = t.z; a4[i][3] = t.w;
                }
                #pragma unroll
                for (int rr = 0; rr < 4; ++rr) {
                    float4 wv = *(const float4*)(wu + (r + rr) * D + j0);
                    #pragma unroll
                    for (int i = 0; i < 4; ++i) {
                        fma4(a4[i][rr], wv, o[i]);
                    }
                }
            }
            #pragma unroll
            for (int i = 0; i < 4; ++i) {
                *(float4*)(out + (row0 + m0 + i) * D + j0) = o[i];
            }
        }
    }
}

extern "C" void kernel_launch(void* const* d_in, const int* in_sizes, int n_in,
                              void* d_out, int out_size, void* d_ws, size_t ws_size,
                              hipStream_t stream) {
    (void)n_in; (void)d_ws; (void)ws_size; (void)out_size;
    const float* x     = (const float*)d_in[0];
    const float* gamma = (const float*)d_in[1];
    const float* beta  = (const float*)d_in[2];
    const float* wd    = (const float*)d_in[3];
    const float* bd    = (const float*)d_in[4];
    const float* wu    = (const float*)d_in[5];
    const float* bu    = (const float*)d_in[6];
    float* out = (float*)d_out;

    const int nrows  = in_sizes[0] / D;          // 16384
    const int blocks = nrows / MROWS;            // 1024
    hipLaunchKernelGGL(adapter_fused, dim3(blocks), dim3(256), 0, stream,
                       x, gamma, beta, wd, bd, wu, bu, out);
}

// Round 3
// 502.731 us; speedup vs baseline: 1.2209x; 1.2209x over previous
//
#include <hip/hip_runtime.h>
#include <math.h>

#define D   2048
#define NR  32
#define SDW 1025   // dwords per hs row (2048 bf16 = 1024 dw + 1 pad) -> row offset 1025%32==1

__device__ __forceinline__ unsigned int f2bf(float f) {
    unsigned int u = __float_as_uint(f);
    return (u + 0x7FFFu + ((u >> 16) & 1u)) >> 16;   // RNE bf16, low 16 bits
}
__device__ __forceinline__ float bflo(unsigned int p) { return __uint_as_float(p << 16); }
__device__ __forceinline__ float bfhi(unsigned int p) { return __uint_as_float(p & 0xFFFF0000u); }

__device__ __forceinline__ void fma4(float a, const float4& w, float4& o) {
    o.x = fmaf(a, w.x, o.x);
    o.y = fmaf(a, w.y, o.y);
    o.z = fmaf(a, w.z, o.z);
    o.w = fmaf(a, w.w, o.w);
}

// ---------------- K1: LayerNorm + down-proj + exact GELU -> a (nrows x 32) ----------------
__global__ __launch_bounds__(256, 4)
void k1_ln_down(const float* __restrict__ x,
                const float* __restrict__ gamma,
                const float* __restrict__ beta,
                const float* __restrict__ wd,
                const float* __restrict__ bd,
                float* __restrict__ aout)
{
    __shared__ unsigned int hs[4 * SDW];   // normalized h, bf16-packed, 4 rows
    __shared__ float yacc[4 * NR];

    const int tid = threadIdx.x;
    const long row0 = (long)blockIdx.x * 4;
    const int m = tid >> 6;      // row within block (wave id)
    const int l = tid & 63;      // lane

    if (tid < 4 * NR) yacc[tid] = 0.0f;

    // ---- load this row's 32 floats ONCE into registers (coalesced 1KB/wave-inst) ----
    const float* xr = x + (row0 + m) * D;
    float4 xv[8];
    #pragma unroll
    for (int it = 0; it < 8; ++it)
        xv[it] = *(const float4*)(xr + it * 256 + l * 4);

    float s = 0.f, s2 = 0.f;
    #pragma unroll
    for (int it = 0; it < 8; ++it) {
        s  += xv[it].x + xv[it].y + xv[it].z + xv[it].w;
        s2 += xv[it].x * xv[it].x + xv[it].y * xv[it].y
            + xv[it].z * xv[it].z + xv[it].w * xv[it].w;
    }
    #pragma unroll
    for (int off = 32; off >= 1; off >>= 1) {
        s  += __shfl_xor(s, off);
        s2 += __shfl_xor(s2, off);
    }
    const float mu   = s * (1.0f / D);
    const float var  = s2 * (1.0f / D) - mu * mu;
    const float rstd = rsqrtf(var + 1e-5f);

    // ---- normalize from registers, store h to LDS as bf16 ----
    #pragma unroll
    for (int it = 0; it < 8; ++it) {
        const int j = it * 256 + l * 4;
        float4 g = *(const float4*)(gamma + j);
        float4 b = *(const float4*)(beta + j);
        float h0 = (xv[it].x - mu) * rstd * g.x + b.x;
        float h1 = (xv[it].y - mu) * rstd * g.y + b.y;
        float h2 = (xv[it].z - mu) * rstd * g.z + b.z;
        float h3 = (xv[it].w - mu) * rstd * g.w + b.w;
        uint2 p;
        p.x = f2bf(h0) | (f2bf(h1) << 16);
        p.y = f2bf(h2) | (f2bf(h3) << 16);
        *(uint2*)(hs + m * SDW + (j >> 1)) = p;
    }
    __syncthreads();

    // ---- down-proj y = h @ wd ----
    {
        const int rg = tid & 7;          // 8 groups x 4 r
        const int mq = (tid >> 3) & 3;   // row
        const int ks = tid >> 5;         // 8 k-splits x 256
        const int r0 = rg * 4;

        float4 acc = make_float4(0.f, 0.f, 0.f, 0.f);
        const int kbeg = ks * 256;
        for (int k = kbeg; k < kbeg + 256; k += 4) {
            const float4* wp = (const float4*)(wd + k * NR + r0);
            float4 w0 = wp[0];
            float4 w1 = wp[8];
            float4 w2 = wp[16];
            float4 w3 = wp[24];
            uint2 hp = *(const uint2*)(hs + mq * SDW + (k >> 1));
            fma4(bflo(hp.x), w0, acc);
            fma4(bfhi(hp.x), w1, acc);
            fma4(bflo(hp.y), w2, acc);
            fma4(bfhi(hp.y), w3, acc);
        }
        // combine ks pairs within the wave (lane ^ 32 flips ks bit 0)
        acc.x += __shfl_xor(acc.x, 32);
        acc.y += __shfl_xor(acc.y, 32);
        acc.z += __shfl_xor(acc.z, 32);
        acc.w += __shfl_xor(acc.w, 32);
        if ((tid & 32) == 0) {
            float* yp = &yacc[mq * NR + r0];
            atomicAdd(yp + 0, acc.x);
            atomicAdd(yp + 1, acc.y);
            atomicAdd(yp + 2, acc.z);
            atomicAdd(yp + 3, acc.w);
        }
    }
    __syncthreads();

    // ---- exact GELU + store a ----
    if (tid < 4 * NR) {
        const float v = yacc[tid] + bd[tid & (NR - 1)];
        const float a = 0.5f * v * (1.0f + erff(v * 0.70710678118654752f));
        aout[row0 * NR + tid] = a;   // a[row][r], rows contiguous
    }
}

// ---------------- K2: up-proj + residual (pure stream, no barriers) ----------------
__global__ __launch_bounds__(256, 4)
void k2_up_res(const float* __restrict__ x,
               const float* __restrict__ aw,
               const float* __restrict__ wu,
               const float* __restrict__ bu,
               float* __restrict__ out)
{
    const int tid = threadIdx.x;
    const long row = (long)blockIdx.x * 4 + (tid >> 6);
    const int l = tid & 63;

    // a[row][0..31] — wave-uniform broadcast loads into registers
    float a[NR];
    const float4* ap = (const float4*)(aw + row * NR);
    #pragma unroll
    for (int q = 0; q < 8; ++q) {
        float4 t = ap[q];
        a[q * 4 + 0] = t.x; a[q * 4 + 1] = t.y;
        a[q * 4 + 2] = t.z; a[q * 4 + 3] = t.w;
    }

    const float* xr   = x + row * D;
    float*       orow = out + row * D;
    #pragma unroll 1
    for (int it = 0; it < 8; ++it) {
        const int j = it * 256 + l * 4;
        float4 o  = *(const float4*)(xr + j);
        float4 bv = *(const float4*)(bu + j);
        o.x += bv.x; o.y += bv.y; o.z += bv.z; o.w += bv.w;
        #pragma unroll
        for (int r = 0; r < NR; ++r) {
            float4 wv = *(const float4*)(wu + r * D + j);
            fma4(a[r], wv, o);
        }
        __builtin_nontemporal_store(o.x, orow + j + 0);
        __builtin_nontemporal_store(o.y, orow + j + 1);
        __builtin_nontemporal_store(o.z, orow + j + 2);
        __builtin_nontemporal_store(o.w, orow + j + 3);
    }
}

extern "C" void kernel_launch(void* const* d_in, const int* in_sizes, int n_in,
                              void* d_out, int out_size, void* d_ws, size_t ws_size,
                              hipStream_t stream) {
    (void)n_in; (void)ws_size; (void)out_size;
    const float* x     = (const float*)d_in[0];
    const float* gamma = (const float*)d_in[1];
    const float* beta  = (const float*)d_in[2];
    const float* wd    = (const float*)d_in[3];
    const float* bd    = (const float*)d_in[4];
    const float* wu    = (const float*)d_in[5];
    const float* bu    = (const float*)d_in[6];
    float* out = (float*)d_out;
    float* aw  = (float*)d_ws;                   // nrows x 32 fp32 = 2 MB

    const int nrows  = in_sizes[0] / D;          // 16384
    const int blocks = nrows / 4;                // 4096
    hipLaunchKernelGGL(k1_ln_down, dim3(blocks), dim3(256), 0, stream,
                       x, gamma, beta, wd, bd, aw);
    hipLaunchKernelGGL(k2_up_res, dim3(blocks), dim3(256), 0, stream,
                       x, aw, wu, bu, out);
}